// Round 1
// baseline (185.975 us; speedup 1.0000x reference)
//
#include <hip/hip_runtime.h>
#include <cstdint>

#define B2 2
#define CCH 256
#define HH 64
#define WW 64
#define HWHW 4096

// ---------------------------------------------------------------------------
// (B,C,H,W) -> (B,HW,C) channel-last transpose for both fmaps.
// grid (HW/32, C/32, 4), block (32,8). z<2 -> fmap1, z>=2 -> fmap2.
// ---------------------------------------------------------------------------
__global__ __launch_bounds__(256) void transpose_cl(
    const float* __restrict__ f1, const float* __restrict__ f2,
    float* __restrict__ f1t, float* __restrict__ f2t) {
  __shared__ float tile[32][33];
  int zz = blockIdx.z;
  const float* src = (zz < 2) ? f1 : f2;
  float* dst = (zz < 2) ? f1t : f2t;
  int b = zz & 1;
  int hw0 = blockIdx.x * 32;
  int c0 = blockIdx.y * 32;
  int tx = threadIdx.x;
  int ty = threadIdx.y;
  const float* sb = src + (size_t)b * CCH * HWHW;
  float* db = dst + (size_t)b * HWHW * CCH;
#pragma unroll
  for (int i = 0; i < 4; i++)
    tile[ty + i * 8][tx] = sb[(size_t)(c0 + ty + i * 8) * HWHW + hw0 + tx];
  __syncthreads();
#pragma unroll
  for (int i = 0; i < 4; i++)
    db[(size_t)(hw0 + ty + i * 8) * CCH + c0 + tx] = tile[tx][ty + i * 8];
}

// ---------------------------------------------------------------------------
// 2x2 avg pool, channel-last, vectorized float4 over channels.
// in: (B, 2Ho, 2Wo, C) -> out: (B, Ho, Wo, C)
// ---------------------------------------------------------------------------
__global__ __launch_bounds__(256) void pool2(
    const float4* __restrict__ in, float4* __restrict__ out, int Ho, int Wo) {
  int idx = blockIdx.x * blockDim.x + threadIdx.x;
  int total = B2 * Ho * Wo * (CCH / 4);
  if (idx >= total) return;
  int c4 = idx & 63;
  int t = idx >> 6;
  int x = t % Wo; t /= Wo;
  int y = t % Ho;
  int b = t / Ho;
  int Wi = Wo * 2;
  int Hi = Ho * 2;
  size_t base = (((size_t)b * Hi + 2 * y) * Wi + 2 * x) * 64 + c4;
  float4 a0 = in[base];
  float4 a1 = in[base + 64];
  float4 a2 = in[base + (size_t)Wi * 64];
  float4 a3 = in[base + (size_t)Wi * 64 + 64];
  float4 r;
  r.x = 0.25f * (a0.x + a1.x + a2.x + a3.x);
  r.y = 0.25f * (a0.y + a1.y + a2.y + a3.y);
  r.z = 0.25f * (a0.z + a1.z + a2.z + a3.z);
  r.w = 0.25f * (a0.w + a1.w + a2.w + a3.w);
  out[idx] = r;
}

// ---------------------------------------------------------------------------
// Main: one block per query (n = b*HW + yi*W + xi), wave = pyramid level.
// Within a wave: 4 taps in flight (lane>>4), 16 lanes per tap each owning
// 16 channels (interleaved so each 16-lane group loads 256B contiguous).
// P[u][v] = dot(f1, f2pool_l[ty,tx]) / 16 over the 10x10 tap patch, then 81
// bilinear combines with the shared fractional weights.
// ---------------------------------------------------------------------------
__global__ __launch_bounds__(256) void sample_k(
    const float* __restrict__ coords,
    const float* __restrict__ f1t,
    const float* __restrict__ f2l0, const float* __restrict__ f2l1,
    const float* __restrict__ f2l2, const float* __restrict__ f2l3,
    float* __restrict__ out) {
  __shared__ float4 f1s[64];
  __shared__ float P[4][100];
  int n = blockIdx.x;
  int b = n >> 12;
  int i = n & 4095;
  int yi = i >> 6, xi = i & 63;
  int tid = threadIdx.x;
  if (tid < 64) f1s[tid] = ((const float4*)(f1t + (size_t)n * CCH))[tid];
  float clx = coords[((size_t)(b * 2 + 0) * HH + yi) * WW + xi];
  float cly = coords[((size_t)(b * 2 + 1) * HH + yi) * WW + xi];
  __syncthreads();

  int l = tid >> 6;    // wave index = level
  int lane = tid & 63;
  int lg = lane >> 4;  // which of 4 concurrent taps
  int l16 = lane & 15; // channel-group lane within tap

  float inv = 1.0f / (float)(1 << l);
  float xl = clx * inv, yl = cly * inv;
  float fx = floorf(xl), fy = floorf(yl);
  int ix0 = (int)fx - 4, iy0 = (int)fy - 4;
  float wx1 = xl - fx, wx0 = 1.0f - wx1;
  float wy1 = yl - fy, wy0 = 1.0f - wy1;
  int Hl = HH >> l, Wl = WW >> l;
  const float* f2 = (l == 0) ? f2l0 : (l == 1) ? f2l1 : (l == 2) ? f2l2 : f2l3;
  const float4* f2b = (const float4*)(f2) + (size_t)b * Hl * Wl * 64;

  // each lane's fmap1 fragment: channels {cc*64 + l16*4 .. +3}, cc=0..3
  float4 f1c0 = f1s[l16];
  float4 f1c1 = f1s[16 + l16];
  float4 f1c2 = f1s[32 + l16];
  float4 f1c3 = f1s[48 + l16];

  for (int it = 0; it < 25; it++) {
    int t = it * 4 + lg;           // tap 0..99
    int u = t / 10;                // x offset index 0..9
    int v = t - u * 10;            // y offset index 0..9
    int tx = ix0 + u, ty = iy0 + v;
    float partial = 0.0f;
    if (((unsigned)tx < (unsigned)Wl) && ((unsigned)ty < (unsigned)Hl)) {
      const float4* tp = f2b + (size_t)(ty * Wl + tx) * 64;
      float4 a0 = tp[l16];
      float4 a1 = tp[16 + l16];
      float4 a2 = tp[32 + l16];
      float4 a3 = tp[48 + l16];
      partial = a0.x * f1c0.x + a0.y * f1c0.y + a0.z * f1c0.z + a0.w * f1c0.w
              + a1.x * f1c1.x + a1.y * f1c1.y + a1.z * f1c1.z + a1.w * f1c1.w
              + a2.x * f1c2.x + a2.y * f1c2.y + a2.z * f1c2.z + a2.w * f1c2.w
              + a3.x * f1c3.x + a3.y * f1c3.y + a3.z * f1c3.z + a3.w * f1c3.w;
    }
    // reduce across the 16 lanes of this tap group (xor masks stay in-group)
    partial += __shfl_xor(partial, 8, 64);
    partial += __shfl_xor(partial, 4, 64);
    partial += __shfl_xor(partial, 2, 64);
    partial += __shfl_xor(partial, 1, 64);
    if (l16 == 0) P[l][t] = partial * 0.0625f;  // 1/sqrt(C) = 1/16
  }
  __syncthreads();

  // 81 outputs per level; k = 9*a + bb with x-offset = a-4, y-offset = bb-4
  {
    int k = lane;  // 0..63 all < 81
    int a = k / 9, bb = k - a * 9;
    float val = wy0 * (wx0 * P[l][a * 10 + bb] + wx1 * P[l][(a + 1) * 10 + bb])
              + wy1 * (wx0 * P[l][a * 10 + bb + 1] + wx1 * P[l][(a + 1) * 10 + bb + 1]);
    out[(size_t)(b * 324 + l * 81 + k) * HWHW + (size_t)yi * WW + xi] = val;
  }
  if (lane < 17) {
    int k = lane + 64;
    int a = k / 9, bb = k - a * 9;
    float val = wy0 * (wx0 * P[l][a * 10 + bb] + wx1 * P[l][(a + 1) * 10 + bb])
              + wy1 * (wx0 * P[l][a * 10 + bb + 1] + wx1 * P[l][(a + 1) * 10 + bb + 1]);
    out[(size_t)(b * 324 + l * 81 + k) * HWHW + (size_t)yi * WW + xi] = val;
  }
}

// ---------------------------------------------------------------------------
extern "C" void kernel_launch(void* const* d_in, const int* in_sizes, int n_in,
                              void* d_out, int out_size, void* d_ws, size_t ws_size,
                              hipStream_t stream) {
  const float* fmap1 = (const float*)d_in[0];
  const float* fmap2 = (const float*)d_in[1];
  const float* coords = (const float*)d_in[2];
  float* out = (float*)d_out;

  char* ws = (char*)d_ws;
  float* f1t  = (float*)(ws);                        // 8 MB   (B,HW,C)
  float* f2l0 = (float*)(ws + ((size_t)8 << 20));    // 8 MB   (B,64,64,C)
  float* f2l1 = (float*)(ws + ((size_t)16 << 20));   // 2 MB   (B,32,32,C)
  float* f2l2 = (float*)(ws + ((size_t)18 << 20));   // 512 KB (B,16,16,C)
  float* f2l3 = (float*)(ws + ((size_t)19 << 20));   // 128 KB (B,8,8,C)

  dim3 tb(32, 8, 1);
  dim3 tg(HWHW / 32, CCH / 32, 4);
  transpose_cl<<<tg, tb, 0, stream>>>(fmap1, fmap2, f1t, f2l0);

  int n1 = B2 * 32 * 32 * (CCH / 4);
  pool2<<<(n1 + 255) / 256, 256, 0, stream>>>((const float4*)f2l0, (float4*)f2l1, 32, 32);
  int n2 = B2 * 16 * 16 * (CCH / 4);
  pool2<<<(n2 + 255) / 256, 256, 0, stream>>>((const float4*)f2l1, (float4*)f2l2, 16, 16);
  int n3 = B2 * 8 * 8 * (CCH / 4);
  pool2<<<(n3 + 255) / 256, 256, 0, stream>>>((const float4*)f2l2, (float4*)f2l3, 8, 8);

  sample_k<<<HWHW * B2, 256, 0, stream>>>(coords, f1t, f2l0, f2l1, f2l2, f2l3, out);
}